// Round 28
// baseline (142.292 us; speedup 1.0000x reference)
//
#include <hip/hip_runtime.h>
#include <hip/hip_bf16.h>

constexpr int NN = 100000;   // nodes
constexpr int NE = 3200000;  // edges
constexpr int BSHIFT = 8;                       // 256 dsts per bucket
constexpr int BSPAN  = 1 << BSHIFT;
constexpr int NB = (NN + BSPAN - 1) >> BSHIFT;  // 391 buckets
constexpr int CAP = 12288;                      // per-bucket slots (r19 verified w/ NBLK=768)
constexpr int NBLK = 768;                       // bucket role blocks (40.1KB branch)
constexpr int THR  = 512;
constexpr int CHUNK = (NE + NBLK - 1) / NBLK;   // 4167 edges per block
constexpr int XB = (NN + 63) / 64;              // 1563 xform role blocks (64 nodes each)
constexpr int XPAD = 68;                        // xform LDS row pitch (floats)
constexpr unsigned int SENT = 0xFFFFFFFFu;      // sentinel: src field = 0x1FFFF

// Edge record (4B): src[0:16] | dl[17:24] | w7[25:31]
__device__ __forceinline__ float w7dec(unsigned int v) {
    return (float)(v >> 25) * (1.0f / 127.0f);
}

// bf16 helpers (RNE)
__device__ __forceinline__ unsigned int bf16pack(float a, float b) {
    unsigned int ua = __float_as_uint(a);
    unsigned int ub = __float_as_uint(b);
    ua += 0x7FFF + ((ua >> 16) & 1);
    ub += 0x7FFF + ((ub >> 16) & 1);
    return (ua >> 16) | (ub & 0xFFFF0000u);
}
__device__ __forceinline__ float bfl(unsigned int u) { return __uint_as_float(u << 16); }
__device__ __forceinline__ float bfh(unsigned int u) { return __uint_as_float(u & 0xFFFF0000u); }

// ---------------------------------------------------------------------------
// Init: zero gcursor.
// ---------------------------------------------------------------------------
__global__ __launch_bounds__(256) void k_init(int* __restrict__ gcursor)
{
    int t = blockIdx.x * 256 + threadIdx.x;
    if (t < NB) gcursor[t] = 0;
}

// ---------------------------------------------------------------------------
// FUSED Pass A (round-28 occupancy push): parity-interleaved bucket/xform
// roles; LDS union shrunk to 40.1KB -> 4 blocks/CU (was 3 at 51.2KB).
// Bucket branch = round-19's verified CHUNK=4167 layout (+ bkt16 reuse);
// xform branch = 64 nodes/block, 8 wave-uniform groups x 8 outputs.
// ---------------------------------------------------------------------------
__global__ __launch_bounds__(THR) void k_bucketxform(
    const int* __restrict__ ei, const float* __restrict__ ew,
    int* __restrict__ gcursor, unsigned int* __restrict__ e_sw,
    const float* __restrict__ x, const float* __restrict__ W1_rel,
    const float* __restrict__ W1_root,
    unsigned int* __restrict__ y1u, float* __restrict__ r1)
{
    __shared__ __align__(16) char smem[40192];
    int tid = threadIdx.x;
    int bid = blockIdx.x;
    bool isBucket; int ridx;
    if (bid < 2 * NBLK) { isBucket = ((bid & 1) == 0); ridx = bid >> 1; }
    else                { isBucket = false; ridx = NBLK + (bid - 2 * NBLK); }

    if (isBucket) {
        // ------------------- bucket branch (40.1KB) -------------------
        unsigned int*   stash = (unsigned int*)  smem;            // 16668
        unsigned short* inv16 = (unsigned short*)(smem + 16672);  // 8334
        unsigned short* bkt16 = (unsigned short*)(smem + 25008);  // 8334
        int* h     = (int*)(smem + 33344);                        // 1564
        int* scan  = (int*)(smem + 34908);                        // 2048
        int* off   = (int*)(smem + 36956);                        // 1564
        int* gbase = (int*)(smem + 38520);                        // 1564 (end 40084)
        int e0 = ridx * CHUNK;
        int cnt = NE - e0; if (cnt > CHUNK) cnt = CHUNK;

        for (int b = tid; b < NB; b += THR) h[b] = 0;
        __syncthreads();
        for (int j = tid; j < cnt; j += THR) {
            int e = e0 + j;
            int d = ei[NE + e];
            unsigned int w7 = (unsigned int)(ew[e] * 127.f + 0.5f);
            stash[j] = (unsigned int)ei[e] | ((unsigned int)(d & (BSPAN - 1)) << 17)
                     | (w7 << 25);
            int b = d >> BSHIFT;
            bkt16[j] = (unsigned short)b;
            atomicAdd(&h[b], 1);
        }
        __syncthreads();
        scan[tid] = (tid < NB) ? h[tid] : 0;
        __syncthreads();
        for (int o = 1; o < THR; o <<= 1) {
            int v = (tid >= o) ? scan[tid - o] : 0;
            __syncthreads();
            scan[tid] += v;
            __syncthreads();
        }
        if (tid < NB) {
            int c = h[tid];
            int r = (c + 7) & ~7;
            gbase[tid] = r ? atomicAdd(&gcursor[tid], r) : 0;
            off[tid] = scan[tid] - c;
        }
        __syncthreads();
        for (int j = tid; j < cnt; j += THR) {
            int b = bkt16[j];
            int p = atomicAdd(&off[b], 1);
            inv16[p] = (unsigned short)j;
        }
        __syncthreads();
        for (int i = tid; i < cnt; i += THR) {
            int j = inv16[i];
            int b = bkt16[j];
            int rel = i - (scan[b] - h[b]);
            e_sw[(size_t)b * CAP + gbase[b] + rel] = stash[j];
        }
        for (int b = tid; b < NB; b += THR) {
            int c = h[b];
            int r = (c + 7) & ~7;
            for (int p = c; p < r; ++p)
                e_sw[(size_t)b * CAP + gbase[b] + p] = SENT;
        }
    } else {
        // ------------------- xform branch (33.8KB) -------------------
        float* xt = (float*)smem;                 // 64*68*4 = 17408
        float* wt = (float*)(smem + 17408);       // 16384
        int n0 = ridx * 64;
        int nend = NN - n0; if (nend > 64) nend = 64;
        if (tid < 512) {                          // 512 float4 pairs
            float4 a = reinterpret_cast<const float4*>(W1_rel)[tid];
            float4 b = reinterpret_cast<const float4*>(W1_root)[tid];
            reinterpret_cast<float4*>(wt)[tid]       = a;
            reinterpret_cast<float4*>(wt)[tid + 512] = b;
        }
        for (int i = tid; i < nend * 16; i += THR) {
            int n = i >> 4, k4 = (i & 15) << 2;
            float4 v = *reinterpret_cast<const float4*>(x + (size_t)(n0 + n) * 64 + k4);
            *reinterpret_cast<float4*>(&xt[n * XPAD + k4]) = v;
        }
        __syncthreads();
        int q = tid >> 6;                        // 0..7, wave-uniform output group
        int n = tid & 63;
        if (n >= nend) return;
        const float* Wb = &wt[q * 8 * 64];       // 8 combined-output rows
        float acc[8];
#pragma unroll
        for (int o = 0; o < 8; ++o) acc[o] = 0.f;
        const float* xrow = &xt[n * XPAD];
#pragma unroll 4
        for (int kt = 0; kt < 16; ++kt) {
            float4 xv = *reinterpret_cast<const float4*>(xrow + kt * 4);
#pragma unroll
            for (int o = 0; o < 8; ++o) {
                const float* w = Wb + o * 64 + kt * 4;
                acc[o] += xv.x * w[0] + xv.y * w[1] + xv.z * w[2] + xv.w * w[3];
            }
        }
        int node = n0 + n;
        if (q < 4) {                              // y1 rel rows q*8..q*8+8 (bf16)
            uint4 a;
            a.x = bf16pack(acc[0], acc[1]);  a.y = bf16pack(acc[2], acc[3]);
            a.z = bf16pack(acc[4], acc[5]);  a.w = bf16pack(acc[6], acc[7]);
            *reinterpret_cast<uint4*>(y1u + (size_t)node * 16 + q * 4) = a;
        } else {                                  // r1 root rows (q-4)*8 (f32)
            float* dst = r1 + (size_t)node * 32 + (q - 4) * 8;
            float4 v0, v1;
            v0.x = acc[0]; v0.y = acc[1]; v0.z = acc[2]; v0.w = acc[3];
            v1.x = acc[4]; v1.y = acc[5]; v1.z = acc[6]; v1.w = acc[7];
            reinterpret_cast<float4*>(dst)[0] = v0;
            reinterpret_cast<float4*>(dst)[1] = v1;
        }
    }
}

// ---------------------------------------------------------------------------
// Pass B (burst sort): ROUND-25/27 version (verified passing).
// ---------------------------------------------------------------------------
__global__ __launch_bounds__(1024) void k_sort(
    const int* __restrict__ gcursor, unsigned int* __restrict__ e_sw,
    int2* __restrict__ rowptr2)
{
    __shared__ unsigned int stash[CAP];           // 49152 B
    __shared__ unsigned short inv16[CAP];         // 24576 B
    __shared__ int hist[BSPAN];
    __shared__ int startp[BSPAN];
    __shared__ int off[BSPAN];
    int b = blockIdx.x, tid = threadIdx.x;
    int cnt = gcursor[b];
    unsigned int* es = e_sw + (size_t)b * CAP;
    if (tid < BSPAN) hist[tid] = 0;
    __syncthreads();
    for (int i = tid; i < cnt; i += 1024) {
        unsigned int v = es[i];
        stash[i] = v;
        if ((v & 0x1FFFFu) != 0x1FFFFu) atomicAdd(&hist[(v >> 17) & 0xFF], 1);
    }
    __syncthreads();
    if (tid < BSPAN) startp[tid] = hist[tid];
    __syncthreads();
    for (int o = 1; o < BSPAN; o <<= 1) {
        int v = (tid < BSPAN && tid >= o) ? startp[tid - o] : 0;
        __syncthreads();
        if (tid < BSPAN) startp[tid] += v;
        __syncthreads();
    }
    int d0 = b << BSHIFT;
    if (tid < BSPAN) {
        int beg_rel = startp[tid] - hist[tid];
        off[tid] = beg_rel;
        int d = d0 + tid;
        if (d < NN) {
            int beg = b * CAP + beg_rel;
            int2 rp; rp.x = beg; rp.y = beg + hist[tid];
            rowptr2[d] = rp;
        }
    }
    __syncthreads();
    for (int i = tid; i < cnt; i += 1024) {
        unsigned int v = stash[i];
        if ((v & 0x1FFFFu) != 0x1FFFFu) {
            int p = atomicAdd(&off[(v >> 17) & 0xFF], 1);
            inv16[p] = (unsigned short)i;
        }
    }
    __syncthreads();
    int tot = startp[BSPAN - 1];
    for (int i = tid; i < tot; i += 1024)
        es[i] = stash[inv16[i]];
}

// ---------------------------------------------------------------------------
// FUSED Reduce1 + node pass: ROUND-27 split-loop version (verified).
// ---------------------------------------------------------------------------
__global__ __launch_bounds__(256) void k_reduce1(
    const int2* __restrict__ rowptr2, const unsigned int* __restrict__ e_sw,
    const unsigned int* __restrict__ y1u, const float* __restrict__ r1,
    const float* __restrict__ b1,
    const float* __restrict__ W2_rel, const float* __restrict__ W2_root,
    float* __restrict__ y2, float* __restrict__ r2)
{
    int idx = blockIdx.x * 256 + threadIdx.x;
    int d = idx >> 3;
    if (d >= NN) return;
    int g = idx & 7;
    int2 rp = rowptr2[d];
    int beg = rp.x, end = rp.y;
    float a0 = 0.f, a1 = 0.f, a2 = 0.f, a3 = 0.f;
    int e = beg;
    int endf = beg + ((end - beg) & ~7);
    for (; e < endf; e += 8) {               // unmasked full batches
        unsigned int pp[8];
#pragma unroll
        for (int u = 0; u < 8; ++u) pp[u] = e_sw[e + u];
        uint2 qq[8];
#pragma unroll
        for (int u = 0; u < 8; ++u)
            qq[u] = *reinterpret_cast<const uint2*>(
                y1u + (size_t)(pp[u] & 0x1FFFF) * 16 + g * 2);
#pragma unroll
        for (int u = 0; u < 8; ++u) {
            float w = w7dec(pp[u]);
            a0 += bfl(qq[u].x) * w; a1 += bfh(qq[u].x) * w;
            a2 += bfl(qq[u].y) * w; a3 += bfh(qq[u].y) * w;
        }
    }
    if (e < end) {                            // one masked epilogue batch
        int lim = end - 1;
        unsigned int pp[8];
#pragma unroll
        for (int u = 0; u < 8; ++u) {
            int ee = e + u;
            pp[u] = e_sw[ee < lim ? ee : lim];
        }
        uint2 qq[8];
#pragma unroll
        for (int u = 0; u < 8; ++u)
            qq[u] = *reinterpret_cast<const uint2*>(
                y1u + (size_t)(pp[u] & 0x1FFFF) * 16 + g * 2);
#pragma unroll
        for (int u = 0; u < 8; ++u) {
            float w = (e + u < end) ? w7dec(pp[u]) : 0.f;
            a0 += bfl(qq[u].x) * w; a1 += bfh(qq[u].x) * w;
            a2 += bfl(qq[u].y) * w; a3 += bfh(qq[u].y) * w;
        }
    }
    float4 rr = *reinterpret_cast<const float4*>(r1 + (size_t)d * 32 + g * 4);
    float4 bb = *reinterpret_cast<const float4*>(b1 + g * 4);
    float h0 = a0 + rr.x + bb.x; h0 = h0 > 0.f ? h0 : 0.f;
    float h1 = a1 + rr.y + bb.y; h1 = h1 > 0.f ? h1 : 0.f;
    float h2 = a2 + rr.z + bb.z; h2 = h2 > 0.f ? h2 : 0.f;
    float h3 = a3 + rr.w + bb.w; h3 = h3 > 0.f ? h3 : 0.f;
    {
        float o[8];
#pragma unroll
        for (int j = 0; j < 8; ++j) {
            float4 w = *reinterpret_cast<const float4*>(W2_rel + j * 32 + g * 4);
            o[j] = h0 * w.x + h1 * w.y + h2 * w.z + h3 * w.w;
        }
#pragma unroll
        for (int s = 1; s < 8; s <<= 1) {
#pragma unroll
            for (int j = 0; j < 8; ++j) o[j] += __shfl_xor(o[j], s);
        }
        if (g < 2) {
            float4 v; v.x = o[g*4+0]; v.y = o[g*4+1]; v.z = o[g*4+2]; v.w = o[g*4+3];
            *reinterpret_cast<float4*>(y2 + (size_t)d * 8 + g * 4) = v;
        }
    }
    {
        float o[8];
#pragma unroll
        for (int j = 0; j < 8; ++j) {
            float4 w = *reinterpret_cast<const float4*>(W2_root + j * 32 + g * 4);
            o[j] = h0 * w.x + h1 * w.y + h2 * w.z + h3 * w.w;
        }
#pragma unroll
        for (int s = 1; s < 8; s <<= 1) {
#pragma unroll
            for (int j = 0; j < 8; ++j) o[j] += __shfl_xor(o[j], s);
        }
        if (g >= 2 && g < 4) {
            int gg = g - 2;
            float4 v; v.x = o[gg*4+0]; v.y = o[gg*4+1]; v.z = o[gg*4+2]; v.w = o[gg*4+3];
            *reinterpret_cast<float4*>(r2 + (size_t)d * 8 + gg * 4) = v;
        }
    }
}

// ---------------------------------------------------------------------------
// FUSED Reduce2 + final: ROUND-27 split-loop version (verified).
// ---------------------------------------------------------------------------
__global__ __launch_bounds__(256) void k_reduce2(
    const int2* __restrict__ rowptr2, const unsigned int* __restrict__ e_sw,
    const float* __restrict__ y2, const float* __restrict__ r2,
    const float* __restrict__ x1, const float* __restrict__ b2,
    const float* __restrict__ W_lin, const float* __restrict__ b_lin,
    float* __restrict__ outv, float* __restrict__ emb)
{
    int idx = blockIdx.x * 256 + threadIdx.x;
    int d = idx >> 1;
    if (d >= NN) return;
    int g = idx & 1;
    int2 rp = rowptr2[d];
    int beg = rp.x, end = rp.y;
    float a0 = 0.f, a1 = 0.f, a2 = 0.f, a3 = 0.f;
    int e = beg;
    int endf = beg + ((end - beg) & ~3);
    for (; e < endf; e += 4) {               // unmasked full batches
        unsigned int pp[4];
#pragma unroll
        for (int u = 0; u < 4; ++u) pp[u] = e_sw[e + u];
        float4 vv[4];
#pragma unroll
        for (int u = 0; u < 4; ++u)
            vv[u] = *reinterpret_cast<const float4*>(
                y2 + (size_t)(pp[u] & 0x1FFFF) * 8 + g * 4);
#pragma unroll
        for (int u = 0; u < 4; ++u) {
            float w = w7dec(pp[u]);
            a0 += vv[u].x * w; a1 += vv[u].y * w;
            a2 += vv[u].z * w; a3 += vv[u].w * w;
        }
    }
    if (e < end) {                            // one masked epilogue batch
        int lim = end - 1;
        unsigned int pp[4];
#pragma unroll
        for (int u = 0; u < 4; ++u) {
            int ee = e + u;
            pp[u] = e_sw[ee < lim ? ee : lim];
        }
        float4 vv[4];
#pragma unroll
        for (int u = 0; u < 4; ++u)
            vv[u] = *reinterpret_cast<const float4*>(
                y2 + (size_t)(pp[u] & 0x1FFFF) * 8 + g * 4);
#pragma unroll
        for (int u = 0; u < 4; ++u) {
            float w = (e + u < end) ? w7dec(pp[u]) : 0.f;
            a0 += vv[u].x * w; a1 += vv[u].y * w;
            a2 += vv[u].z * w; a3 += vv[u].w * w;
        }
    }
    float4 rr = *reinterpret_cast<const float4*>(r2 + (size_t)d * 8 + g * 4);
    float4 bb = *reinterpret_cast<const float4*>(b2 + g * 4);
    float h0 = a0 + rr.x + bb.x;
    float h1 = a1 + rr.y + bb.y;
    float h2 = a2 + rr.z + bb.z;
    float h3 = a3 + rr.w + bb.w;
    float m = fmaxf(fmaxf(h0, h1), fmaxf(h2, h3));
    m = fmaxf(m, __shfl_xor(m, 1));
    float s = __expf(h0 - m) + __expf(h1 - m) + __expf(h2 - m) + __expf(h3 - m);
    s += __shfl_xor(s, 1);
    float lse = __logf(s);
    float e0 = h0 - m - lse, e1 = h1 - m - lse, e2 = h2 - m - lse, e3 = h3 - m - lse;
    float4 ev; ev.x = e0; ev.y = e1; ev.z = e2; ev.w = e3;
    *reinterpret_cast<float4*>(emb + (size_t)d * 8 + g * 4) = ev;
    float4 wl = *reinterpret_cast<const float4*>(W_lin + g * 4);
    float p = e0 * wl.x + e1 * wl.y + e2 * wl.z + e3 * wl.w;
    p += __shfl_xor(p, 1);
    if (g == 0) {
        float acc = p + b_lin[0] + x1[d] * W_lin[8];
        outv[d] = acc > 0.f ? acc : 0.f;
    }
}

// ---------------------------------------------------------------------------
extern "C" void kernel_launch(void* const* d_in, const int* in_sizes, int n_in,
                              void* d_out, int out_size, void* d_ws, size_t ws_size,
                              hipStream_t stream) {
    const float* x      = (const float*)d_in[0];
    const int*   ei     = (const int*)  d_in[1];
    const float* ew     = (const float*)d_in[2];
    const float* x1     = (const float*)d_in[3];
    const float* W1_rel = (const float*)d_in[4];
    const float* b1     = (const float*)d_in[5];
    const float* W1_root= (const float*)d_in[6];
    const float* W2_rel = (const float*)d_in[7];
    const float* b2     = (const float*)d_in[8];
    const float* W2_root= (const float*)d_in[9];
    const float* W_lin  = (const float*)d_in[10];
    const float* b_lin  = (const float*)d_in[11];

    float* ws    = (float*)d_ws;
    unsigned int* y1u = (unsigned int*)ws;              // N*16 uints (bf16 y1, 6.4MB)
    float* r1    = (float*)(y1u + (size_t)NN * 16);     // N*32
    float* y2    = r1 + (size_t)NN * 32;                // N*8
    float* r2    = y2 + (size_t)NN * 8;                 // N*8
    int*   gcursor = (int*)(r2 + (size_t)NN * 8);       // NB, padded to 1024
    int2*  rowptr2 = (int2*)(gcursor + 1024);           // NN int2
    unsigned int* e_sw = (unsigned int*)(rowptr2 + NN); // NB*CAP u32 (19.2MB)

    float* outv = (float*)d_out;             // N   (output 0)
    float* emb  = outv + NN;                 // N*8 (output 1)

    k_init<<<2, 256, 0, stream>>>(gcursor);
    k_bucketxform<<<2 * NBLK + (XB - NBLK), THR, 0, stream>>>(
        ei, ew, gcursor, e_sw, x, W1_rel, W1_root, y1u, r1);
    k_sort<<<NB, 1024, 0, stream>>>(gcursor, e_sw, rowptr2);
    k_reduce1<<<(NN * 8 + 255) / 256, 256, 0, stream>>>(
        rowptr2, e_sw, y1u, r1, b1, W2_rel, W2_root, y2, r2);
    k_reduce2<<<(NN * 2 + 255) / 256, 256, 0, stream>>>(
        rowptr2, e_sw, y2, r2, x1, b2, W_lin, b_lin, outv, emb);
}

// Round 29
// 134.266 us; speedup vs baseline: 1.0598x; 1.0598x over previous
//
#include <hip/hip_runtime.h>
#include <hip/hip_bf16.h>

constexpr int NN = 100000;   // nodes
constexpr int NE = 3200000;  // edges
constexpr int BSHIFT = 8;                       // 256 dsts per bucket
constexpr int BSPAN  = 1 << BSHIFT;
constexpr int NB = (NN + BSPAN - 1) >> BSHIFT;  // 391 buckets
constexpr int CAP = 12288;                      // per-bucket slots (round-25 verified)
constexpr int NBLK = 640;                       // bucket role blocks (46.7KB branch)
constexpr int THR  = 512;
constexpr int CHUNK = NE / NBLK;                // 5000 edges per block (exact)
constexpr int XB = (NN + 127) / 128;            // 782 xform role blocks
constexpr int XPAD = 68;                        // xform LDS row pitch (floats)
constexpr unsigned int SENT = 0xFFFFFFFFu;      // sentinel: src field = 0x1FFFF

// Edge record (4B): src[0:16] | dl[17:24] | w7[25:31]
__device__ __forceinline__ float w7dec(unsigned int v) {
    return (float)(v >> 25) * (1.0f / 127.0f);
}

// bf16 helpers (RNE)
__device__ __forceinline__ unsigned int bf16pack(float a, float b) {
    unsigned int ua = __float_as_uint(a);
    unsigned int ub = __float_as_uint(b);
    ua += 0x7FFF + ((ua >> 16) & 1);
    ub += 0x7FFF + ((ub >> 16) & 1);
    return (ua >> 16) | (ub & 0xFFFF0000u);
}
__device__ __forceinline__ float bfl(unsigned int u) { return __uint_as_float(u << 16); }
__device__ __forceinline__ float bfh(unsigned int u) { return __uint_as_float(u & 0xFFFF0000u); }

// ---------------------------------------------------------------------------
// Init: zero gcursor.
// ---------------------------------------------------------------------------
__global__ __launch_bounds__(256) void k_init(int* __restrict__ gcursor)
{
    int t = blockIdx.x * 256 + threadIdx.x;
    if (t < NB) gcursor[t] = 0;
}

// ---------------------------------------------------------------------------
// FUSED Pass A (round-27 exact, best verified): parity-interleaved
// bucket/xform roles, round8 (32B) reservations, 51.2KB union -> 3/CU.
// Round-28 lesson: shrinking both branches for 4/CU raised VGPR 40->56 and
// broke the role pairing (occupancy 43->28%); 3/CU interleave is optimal.
// ---------------------------------------------------------------------------
__global__ __launch_bounds__(THR) void k_bucketxform(
    const int* __restrict__ ei, const float* __restrict__ ew,
    int* __restrict__ gcursor, unsigned int* __restrict__ e_sw,
    const float* __restrict__ x, const float* __restrict__ W1_rel,
    const float* __restrict__ W1_root,
    unsigned int* __restrict__ y1u, float* __restrict__ r1)
{
    __shared__ __align__(16) char smem[51200];
    int tid = threadIdx.x;
    int bid = blockIdx.x;
    bool isBucket; int ridx;
    if (bid < 2 * NBLK) { isBucket = ((bid & 1) == 0); ridx = bid >> 1; }
    else                { isBucket = false; ridx = NBLK + (bid - 2 * NBLK); }

    if (isBucket) {
        // ------------------- bucket branch (46.7KB) -------------------
        unsigned int*   stash = (unsigned int*)  smem;            // 20000
        unsigned short* inv16 = (unsigned short*)(smem + 20000);  // 10000
        unsigned short* bkt16 = (unsigned short*)(smem + 30000);  // 10000
        int* h     = (int*)(smem + 40000);                        // 1564
        int* scan  = (int*)(smem + 41568);                        // 2048
        int* off   = (int*)(smem + 43616);                        // 1564
        int* gbase = (int*)(smem + 45184);                        // 1564
        int e0 = ridx * CHUNK;
        int cnt = NE - e0; if (cnt > CHUNK) cnt = CHUNK;

        for (int b = tid; b < NB; b += THR) h[b] = 0;
        __syncthreads();
        for (int j = tid; j < cnt; j += THR) {
            int e = e0 + j;
            int d = ei[NE + e];
            unsigned int w7 = (unsigned int)(ew[e] * 127.f + 0.5f);
            stash[j] = (unsigned int)ei[e] | ((unsigned int)(d & (BSPAN - 1)) << 17)
                     | (w7 << 25);
            int b = d >> BSHIFT;
            bkt16[j] = (unsigned short)b;
            atomicAdd(&h[b], 1);
        }
        __syncthreads();
        scan[tid] = (tid < NB) ? h[tid] : 0;
        __syncthreads();
        for (int o = 1; o < THR; o <<= 1) {
            int v = (tid >= o) ? scan[tid - o] : 0;
            __syncthreads();
            scan[tid] += v;
            __syncthreads();
        }
        if (tid < NB) {
            int c = h[tid];
            int r = (c + 7) & ~7;
            gbase[tid] = r ? atomicAdd(&gcursor[tid], r) : 0;
            off[tid] = scan[tid] - c;
        }
        __syncthreads();
        for (int j = tid; j < cnt; j += THR) {
            int b = bkt16[j];
            int p = atomicAdd(&off[b], 1);
            inv16[p] = (unsigned short)j;
        }
        __syncthreads();
        for (int i = tid; i < cnt; i += THR) {
            int j = inv16[i];
            int b = bkt16[j];
            int rel = i - (scan[b] - h[b]);
            e_sw[(size_t)b * CAP + gbase[b] + rel] = stash[j];
        }
        for (int b = tid; b < NB; b += THR) {
            int c = h[b];
            int r = (c + 7) & ~7;
            for (int p = c; p < r; ++p)
                e_sw[(size_t)b * CAP + gbase[b] + p] = SENT;
        }
    } else {
        // ------------------- xform branch (51.2KB) -------------------
        float* xt = (float*)smem;                 // 128*68*4 = 34816
        float* wt = (float*)(smem + 34816);       // 16384
        int n0 = ridx * 128;
        int nend = NN - n0; if (nend > 128) nend = 128;
        {
            int i = tid;   // exactly 512 float4 pairs
            float4 a = reinterpret_cast<const float4*>(W1_rel)[i];
            float4 b = reinterpret_cast<const float4*>(W1_root)[i];
            reinterpret_cast<float4*>(wt)[i]       = a;
            reinterpret_cast<float4*>(wt)[i + 512] = b;
        }
        for (int i = tid; i < nend * 16; i += THR) {
            int n = i >> 4, k4 = (i & 15) << 2;
            float4 v = *reinterpret_cast<const float4*>(x + (size_t)(n0 + n) * 64 + k4);
            *reinterpret_cast<float4*>(&xt[n * XPAD + k4]) = v;
        }
        __syncthreads();
        int q = tid >> 7;                        // 0..3, wave-uniform
        int n = tid & 127;
        if (n >= nend) return;
        const float* Wb = &wt[q * 16 * 64];
        float acc[16];
#pragma unroll
        for (int o = 0; o < 16; ++o) acc[o] = 0.f;
        const float* xrow = &xt[n * XPAD];
#pragma unroll 4
        for (int kt = 0; kt < 16; ++kt) {
            float4 xv = *reinterpret_cast<const float4*>(xrow + kt * 4);
#pragma unroll
            for (int o = 0; o < 16; ++o) {
                const float* w = Wb + o * 64 + kt * 4;
                acc[o] += xv.x * w[0] + xv.y * w[1] + xv.z * w[2] + xv.w * w[3];
            }
        }
        int node = n0 + n;
        if (q < 2) {
            uint4 a, b;
            a.x = bf16pack(acc[0],  acc[1]);  a.y = bf16pack(acc[2],  acc[3]);
            a.z = bf16pack(acc[4],  acc[5]);  a.w = bf16pack(acc[6],  acc[7]);
            b.x = bf16pack(acc[8],  acc[9]);  b.y = bf16pack(acc[10], acc[11]);
            b.z = bf16pack(acc[12], acc[13]); b.w = bf16pack(acc[14], acc[15]);
            unsigned int* dst = y1u + (size_t)node * 16 + q * 8;
            *reinterpret_cast<uint4*>(dst)     = a;
            *reinterpret_cast<uint4*>(dst + 4) = b;
        } else {
            float* dst = r1 + (size_t)node * 32 + (q - 2) * 16;
#pragma unroll
            for (int i = 0; i < 4; ++i) {
                float4 v; v.x = acc[4*i]; v.y = acc[4*i+1]; v.z = acc[4*i+2]; v.w = acc[4*i+3];
                reinterpret_cast<float4*>(dst)[i] = v;
            }
        }
    }
}

// ---------------------------------------------------------------------------
// Pass B (burst sort): ROUND-25/27 version (verified passing).
// ---------------------------------------------------------------------------
__global__ __launch_bounds__(1024) void k_sort(
    const int* __restrict__ gcursor, unsigned int* __restrict__ e_sw,
    int2* __restrict__ rowptr2)
{
    __shared__ unsigned int stash[CAP];           // 49152 B
    __shared__ unsigned short inv16[CAP];         // 24576 B
    __shared__ int hist[BSPAN];
    __shared__ int startp[BSPAN];
    __shared__ int off[BSPAN];
    int b = blockIdx.x, tid = threadIdx.x;
    int cnt = gcursor[b];
    unsigned int* es = e_sw + (size_t)b * CAP;
    if (tid < BSPAN) hist[tid] = 0;
    __syncthreads();
    for (int i = tid; i < cnt; i += 1024) {
        unsigned int v = es[i];
        stash[i] = v;
        if ((v & 0x1FFFFu) != 0x1FFFFu) atomicAdd(&hist[(v >> 17) & 0xFF], 1);
    }
    __syncthreads();
    if (tid < BSPAN) startp[tid] = hist[tid];
    __syncthreads();
    for (int o = 1; o < BSPAN; o <<= 1) {
        int v = (tid < BSPAN && tid >= o) ? startp[tid - o] : 0;
        __syncthreads();
        if (tid < BSPAN) startp[tid] += v;
        __syncthreads();
    }
    int d0 = b << BSHIFT;
    if (tid < BSPAN) {
        int beg_rel = startp[tid] - hist[tid];
        off[tid] = beg_rel;
        int d = d0 + tid;
        if (d < NN) {
            int beg = b * CAP + beg_rel;
            int2 rp; rp.x = beg; rp.y = beg + hist[tid];
            rowptr2[d] = rp;
        }
    }
    __syncthreads();
    for (int i = tid; i < cnt; i += 1024) {
        unsigned int v = stash[i];
        if ((v & 0x1FFFFu) != 0x1FFFFu) {
            int p = atomicAdd(&off[(v >> 17) & 0xFF], 1);
            inv16[p] = (unsigned short)i;
        }
    }
    __syncthreads();
    int tot = startp[BSPAN - 1];
    for (int i = tid; i < tot; i += 1024)
        es[i] = stash[inv16[i]];
}

// ---------------------------------------------------------------------------
// FUSED Reduce1 + node pass: ROUND-27 split-loop version (verified).
// ---------------------------------------------------------------------------
__global__ __launch_bounds__(256) void k_reduce1(
    const int2* __restrict__ rowptr2, const unsigned int* __restrict__ e_sw,
    const unsigned int* __restrict__ y1u, const float* __restrict__ r1,
    const float* __restrict__ b1,
    const float* __restrict__ W2_rel, const float* __restrict__ W2_root,
    float* __restrict__ y2, float* __restrict__ r2)
{
    int idx = blockIdx.x * 256 + threadIdx.x;
    int d = idx >> 3;
    if (d >= NN) return;
    int g = idx & 7;
    int2 rp = rowptr2[d];
    int beg = rp.x, end = rp.y;
    float a0 = 0.f, a1 = 0.f, a2 = 0.f, a3 = 0.f;
    int e = beg;
    int endf = beg + ((end - beg) & ~7);
    for (; e < endf; e += 8) {               // unmasked full batches
        unsigned int pp[8];
#pragma unroll
        for (int u = 0; u < 8; ++u) pp[u] = e_sw[e + u];
        uint2 qq[8];
#pragma unroll
        for (int u = 0; u < 8; ++u)
            qq[u] = *reinterpret_cast<const uint2*>(
                y1u + (size_t)(pp[u] & 0x1FFFF) * 16 + g * 2);
#pragma unroll
        for (int u = 0; u < 8; ++u) {
            float w = w7dec(pp[u]);
            a0 += bfl(qq[u].x) * w; a1 += bfh(qq[u].x) * w;
            a2 += bfl(qq[u].y) * w; a3 += bfh(qq[u].y) * w;
        }
    }
    if (e < end) {                            // one masked epilogue batch
        int lim = end - 1;
        unsigned int pp[8];
#pragma unroll
        for (int u = 0; u < 8; ++u) {
            int ee = e + u;
            pp[u] = e_sw[ee < lim ? ee : lim];
        }
        uint2 qq[8];
#pragma unroll
        for (int u = 0; u < 8; ++u)
            qq[u] = *reinterpret_cast<const uint2*>(
                y1u + (size_t)(pp[u] & 0x1FFFF) * 16 + g * 2);
#pragma unroll
        for (int u = 0; u < 8; ++u) {
            float w = (e + u < end) ? w7dec(pp[u]) : 0.f;
            a0 += bfl(qq[u].x) * w; a1 += bfh(qq[u].x) * w;
            a2 += bfl(qq[u].y) * w; a3 += bfh(qq[u].y) * w;
        }
    }
    float4 rr = *reinterpret_cast<const float4*>(r1 + (size_t)d * 32 + g * 4);
    float4 bb = *reinterpret_cast<const float4*>(b1 + g * 4);
    float h0 = a0 + rr.x + bb.x; h0 = h0 > 0.f ? h0 : 0.f;
    float h1 = a1 + rr.y + bb.y; h1 = h1 > 0.f ? h1 : 0.f;
    float h2 = a2 + rr.z + bb.z; h2 = h2 > 0.f ? h2 : 0.f;
    float h3 = a3 + rr.w + bb.w; h3 = h3 > 0.f ? h3 : 0.f;
    {
        float o[8];
#pragma unroll
        for (int j = 0; j < 8; ++j) {
            float4 w = *reinterpret_cast<const float4*>(W2_rel + j * 32 + g * 4);
            o[j] = h0 * w.x + h1 * w.y + h2 * w.z + h3 * w.w;
        }
#pragma unroll
        for (int s = 1; s < 8; s <<= 1) {
#pragma unroll
            for (int j = 0; j < 8; ++j) o[j] += __shfl_xor(o[j], s);
        }
        if (g < 2) {
            float4 v; v.x = o[g*4+0]; v.y = o[g*4+1]; v.z = o[g*4+2]; v.w = o[g*4+3];
            *reinterpret_cast<float4*>(y2 + (size_t)d * 8 + g * 4) = v;
        }
    }
    {
        float o[8];
#pragma unroll
        for (int j = 0; j < 8; ++j) {
            float4 w = *reinterpret_cast<const float4*>(W2_root + j * 32 + g * 4);
            o[j] = h0 * w.x + h1 * w.y + h2 * w.z + h3 * w.w;
        }
#pragma unroll
        for (int s = 1; s < 8; s <<= 1) {
#pragma unroll
            for (int j = 0; j < 8; ++j) o[j] += __shfl_xor(o[j], s);
        }
        if (g >= 2 && g < 4) {
            int gg = g - 2;
            float4 v; v.x = o[gg*4+0]; v.y = o[gg*4+1]; v.z = o[gg*4+2]; v.w = o[gg*4+3];
            *reinterpret_cast<float4*>(r2 + (size_t)d * 8 + gg * 4) = v;
        }
    }
}

// ---------------------------------------------------------------------------
// FUSED Reduce2 + final: ROUND-27 split-loop version (verified).
// ---------------------------------------------------------------------------
__global__ __launch_bounds__(256) void k_reduce2(
    const int2* __restrict__ rowptr2, const unsigned int* __restrict__ e_sw,
    const float* __restrict__ y2, const float* __restrict__ r2,
    const float* __restrict__ x1, const float* __restrict__ b2,
    const float* __restrict__ W_lin, const float* __restrict__ b_lin,
    float* __restrict__ outv, float* __restrict__ emb)
{
    int idx = blockIdx.x * 256 + threadIdx.x;
    int d = idx >> 1;
    if (d >= NN) return;
    int g = idx & 1;
    int2 rp = rowptr2[d];
    int beg = rp.x, end = rp.y;
    float a0 = 0.f, a1 = 0.f, a2 = 0.f, a3 = 0.f;
    int e = beg;
    int endf = beg + ((end - beg) & ~3);
    for (; e < endf; e += 4) {               // unmasked full batches
        unsigned int pp[4];
#pragma unroll
        for (int u = 0; u < 4; ++u) pp[u] = e_sw[e + u];
        float4 vv[4];
#pragma unroll
        for (int u = 0; u < 4; ++u)
            vv[u] = *reinterpret_cast<const float4*>(
                y2 + (size_t)(pp[u] & 0x1FFFF) * 8 + g * 4);
#pragma unroll
        for (int u = 0; u < 4; ++u) {
            float w = w7dec(pp[u]);
            a0 += vv[u].x * w; a1 += vv[u].y * w;
            a2 += vv[u].z * w; a3 += vv[u].w * w;
        }
    }
    if (e < end) {                            // one masked epilogue batch
        int lim = end - 1;
        unsigned int pp[4];
#pragma unroll
        for (int u = 0; u < 4; ++u) {
            int ee = e + u;
            pp[u] = e_sw[ee < lim ? ee : lim];
        }
        float4 vv[4];
#pragma unroll
        for (int u = 0; u < 4; ++u)
            vv[u] = *reinterpret_cast<const float4*>(
                y2 + (size_t)(pp[u] & 0x1FFFF) * 8 + g * 4);
#pragma unroll
        for (int u = 0; u < 4; ++u) {
            float w = (e + u < end) ? w7dec(pp[u]) : 0.f;
            a0 += vv[u].x * w; a1 += vv[u].y * w;
            a2 += vv[u].z * w; a3 += vv[u].w * w;
        }
    }
    float4 rr = *reinterpret_cast<const float4*>(r2 + (size_t)d * 8 + g * 4);
    float4 bb = *reinterpret_cast<const float4*>(b2 + g * 4);
    float h0 = a0 + rr.x + bb.x;
    float h1 = a1 + rr.y + bb.y;
    float h2 = a2 + rr.z + bb.z;
    float h3 = a3 + rr.w + bb.w;
    float m = fmaxf(fmaxf(h0, h1), fmaxf(h2, h3));
    m = fmaxf(m, __shfl_xor(m, 1));
    float s = __expf(h0 - m) + __expf(h1 - m) + __expf(h2 - m) + __expf(h3 - m);
    s += __shfl_xor(s, 1);
    float lse = __logf(s);
    float e0 = h0 - m - lse, e1 = h1 - m - lse, e2 = h2 - m - lse, e3 = h3 - m - lse;
    float4 ev; ev.x = e0; ev.y = e1; ev.z = e2; ev.w = e3;
    *reinterpret_cast<float4*>(emb + (size_t)d * 8 + g * 4) = ev;
    float4 wl = *reinterpret_cast<const float4*>(W_lin + g * 4);
    float p = e0 * wl.x + e1 * wl.y + e2 * wl.z + e3 * wl.w;
    p += __shfl_xor(p, 1);
    if (g == 0) {
        float acc = p + b_lin[0] + x1[d] * W_lin[8];
        outv[d] = acc > 0.f ? acc : 0.f;
    }
}

// ---------------------------------------------------------------------------
extern "C" void kernel_launch(void* const* d_in, const int* in_sizes, int n_in,
                              void* d_out, int out_size, void* d_ws, size_t ws_size,
                              hipStream_t stream) {
    const float* x      = (const float*)d_in[0];
    const int*   ei     = (const int*)  d_in[1];
    const float* ew     = (const float*)d_in[2];
    const float* x1     = (const float*)d_in[3];
    const float* W1_rel = (const float*)d_in[4];
    const float* b1     = (const float*)d_in[5];
    const float* W1_root= (const float*)d_in[6];
    const float* W2_rel = (const float*)d_in[7];
    const float* b2     = (const float*)d_in[8];
    const float* W2_root= (const float*)d_in[9];
    const float* W_lin  = (const float*)d_in[10];
    const float* b_lin  = (const float*)d_in[11];

    float* ws    = (float*)d_ws;
    unsigned int* y1u = (unsigned int*)ws;              // N*16 uints (bf16 y1, 6.4MB)
    float* r1    = (float*)(y1u + (size_t)NN * 16);     // N*32
    float* y2    = r1 + (size_t)NN * 32;                // N*8
    float* r2    = y2 + (size_t)NN * 8;                 // N*8
    int*   gcursor = (int*)(r2 + (size_t)NN * 8);       // NB, padded to 1024
    int2*  rowptr2 = (int2*)(gcursor + 1024);           // NN int2
    unsigned int* e_sw = (unsigned int*)(rowptr2 + NN); // NB*CAP u32 (19.2MB)

    float* outv = (float*)d_out;             // N   (output 0)
    float* emb  = outv + NN;                 // N*8 (output 1)

    k_init<<<2, 256, 0, stream>>>(gcursor);
    k_bucketxform<<<2 * NBLK + (XB - NBLK), THR, 0, stream>>>(
        ei, ew, gcursor, e_sw, x, W1_rel, W1_root, y1u, r1);
    k_sort<<<NB, 1024, 0, stream>>>(gcursor, e_sw, rowptr2);
    k_reduce1<<<(NN * 8 + 255) / 256, 256, 0, stream>>>(
        rowptr2, e_sw, y1u, r1, b1, W2_rel, W2_root, y2, r2);
    k_reduce2<<<(NN * 2 + 255) / 256, 256, 0, stream>>>(
        rowptr2, e_sw, y2, r2, x1, b2, W_lin, b_lin, outv, emb);
}